// Round 22
// baseline (270.041 us; speedup 1.0000x reference)
//
#include <hip/hip_runtime.h>

#define Nn     20000
#define IN_CH  512
#define C1     512      // H1*HID
#define H1n    8
#define HIDn   64
#define OUT_CH 16
#define En     320000
#define EPn    340000   // E + N self-loops
#define NEG    0.2f

typedef __attribute__((ext_vector_type(8))) short bf16x8;
typedef __attribute__((ext_vector_type(4))) float f32x4;

// ---------------- fp32 -> bf16 helpers (RNE) --------------------------------
__device__ inline unsigned short bf16_rne(float f) {
  unsigned int u = __float_as_uint(f);
  return (unsigned short)((u + 0x7fffu + ((u >> 16) & 1u)) >> 16);
}
__device__ inline float bf16_f(unsigned short u) {
  return __uint_as_float(((unsigned int)u) << 16);
}

// packed f32x8 -> bf16x8 via hardware cvt_pk (RNE)
__device__ inline bf16x8 pack8(float4 f0, float4 f1) {
  unsigned int r0, r1, r2, r3;
  asm("v_cvt_pk_bf16_f32 %0, %1, %2" : "=v"(r0) : "v"(f0.x), "v"(f0.y));
  asm("v_cvt_pk_bf16_f32 %0, %1, %2" : "=v"(r1) : "v"(f0.z), "v"(f0.w));
  asm("v_cvt_pk_bf16_f32 %0, %1, %2" : "=v"(r2) : "v"(f1.x), "v"(f1.y));
  asm("v_cvt_pk_bf16_f32 %0, %1, %2" : "=v"(r3) : "v"(f1.z), "v"(f1.w));
  union { unsigned int u[4]; bf16x8 v; } un;
  un.u[0] = r0; un.u[1] = r1; un.u[2] = r2; un.u[3] = r3;
  return un.v;
}

// W1, W2 -> bf16 + edge histogram, one launch (cnt pre-zeroed by memset)
#define NW8  (C1 * IN_CH / 8)
#define NW28 (OUT_CH * C1 / 8)
#define NH4  (EPn / 4)
__global__ __launch_bounds__(256) void cvtwh_kernel(
    const float* __restrict__ W1, unsigned short* __restrict__ w1b,
    const float* __restrict__ W2, unsigned short* __restrict__ w2b,
    const int* __restrict__ ei, int* __restrict__ cnt)
{
  int i = blockIdx.x * 256 + threadIdx.x;
  const float* in; unsigned short* ob; int idx;
  if (i < NW8) { in = W1; ob = w1b; idx = i; }
  else if (i < NW8 + NW28) { in = W2; ob = w2b; idx = i - NW8; }
  else if (i < NW8 + NW28 + NH4) {
    int e4 = (i - NW8 - NW28) * 4;      // En, EPn divisible by 4
    if (e4 < En) {
      int4 dv = *(const int4*)&ei[En + e4];
      atomicAdd(&cnt[dv.x], 1); atomicAdd(&cnt[dv.y], 1);
      atomicAdd(&cnt[dv.z], 1); atomicAdd(&cnt[dv.w], 1);
    } else {
      int d = e4 - En;
      atomicAdd(&cnt[d], 1);     atomicAdd(&cnt[d + 1], 1);
      atomicAdd(&cnt[d + 2], 1); atomicAdd(&cnt[d + 3], 1);
    }
    return;
  } else return;
  float4 f0 = ((const float4*)in)[idx * 2];
  float4 f1 = ((const float4*)in)[idx * 2 + 1];
  float f[8] = {f0.x, f0.y, f0.z, f0.w, f1.x, f1.y, f1.z, f1.w};
  unsigned short h[8];
#pragma unroll
  for (int j = 0; j < 8; j++) h[j] = bf16_rne(f[j]);
  ushort4 hv0 = {h[0], h[1], h[2], h[3]}, hv1 = {h[4], h[5], h[6], h[7]};
  ((ushort4*)ob)[idx * 2] = hv0; ((ushort4*)ob)[idx * 2 + 1] = hv1;
}

// ------ GEMM1: h1b[N,512](bf16) = x(f32) @ W1b^T + fused logits -------------
// Round-19 form: 128x128 tile, double-buffered LDS, XCD-aware mapping.
#define GLL(gp, lp) __builtin_amdgcn_global_load_lds( \
    (const __attribute__((address_space(1))) void*)(gp), \
    (__attribute__((address_space(3))) void*)(lp), 16, 0, 0)

#define SWZ(c)  ((c) ^ (((c) >> 3) & 3))   // bf16 rows: 4 chunks/row
#define SWZA(c) ((c) ^ (((c) >> 3) & 7))   // f32 rows: 8 chunks/row

__global__ __launch_bounds__(256, 3) void gemm1_mfma(
    const float* __restrict__ Af, const unsigned short* __restrict__ Bb,
    const float* __restrict__ attS, const float* __restrict__ attD,
    unsigned short* __restrict__ Cb, float* __restrict__ as1, float* __restrict__ ad1)
{
  __shared__ float sAf[2][128 * 32];          // 2 x 16 KB
  __shared__ unsigned short sB[2][128 * 32];  // 2 x 8 KB
  int t = threadIdx.x;
  int wgid = blockIdx.x;
  int bm = (wgid & 7) + 8 * (wgid >> 5);
  int bn = (wgid >> 3) & 3;
  if (bm >= 157) return;               // 12 pad blocks
  int lane = t & 63, w = t >> 6;

  int acb[4]; size_t aoff[4];
#pragma unroll
  for (int q = 0; q < 4; q++) {
    int slot = w * 256 + q * 64 + lane;
    acb[q] = w * 256 + q * 64;             // wave-uniform LDS base chunk
    int cs = SWZA(slot);
    int ra = bm * 128 + (cs >> 3); if (ra > Nn - 1) ra = Nn - 1;
    aoff[q] = (size_t)ra * IN_CH + (cs & 7) * 4;
  }
  int slot0 = w * 128 + lane, slot1 = slot0 + 64;
  int bcb0 = w * 128, bcb1 = w * 128 + 64;
  int cs0 = SWZ(slot0), cs1 = SWZ(slot1);
  int br0 = bn * 128 + (cs0 >> 2);
  int br1 = bn * 128 + (cs1 >> 2);
  size_t offB0 = (size_t)br0 * IN_CH + (cs0 & 3) * 8;
  size_t offB1 = (size_t)br1 * IN_CH + (cs1 & 3) * 8;

  int wm = (w >> 1) * 64, wn = (w & 1) * 64;
  int lr = lane & 15, kb = lane >> 4;

  f32x4 acc[4][4] = {};

  GLL(Af + aoff[0], sAf[0] + acb[0] * 4);
  GLL(Af + aoff[1], sAf[0] + acb[1] * 4);
  GLL(Af + aoff[2], sAf[0] + acb[2] * 4);
  GLL(Af + aoff[3], sAf[0] + acb[3] * 4);
  GLL(Bb + offB0, sB[0] + bcb0 * 8);
  GLL(Bb + offB1, sB[0] + bcb1 * 8);
  __syncthreads();

#pragma unroll 2
  for (int it = 0; it < 16; it++) {
    int cur = it & 1;
    const float* Ac = sAf[cur];
    const unsigned short* Bc = sB[cur];
    bf16x8 ah[4], bh[4];
#pragma unroll
    for (int i = 0; i < 4; i++) {
      int c0 = (wm + i * 16 + lr) * 8 + kb * 2;
      float4 f0 = *(const float4*)&Ac[SWZA(c0) * 4];
      float4 f1 = *(const float4*)&Ac[SWZA(c0 + 1) * 4];
      ah[i] = pack8(f0, f1);
      int rcb = (wn + i * 16 + lr) * 4 + kb;
      bh[i] = *(const bf16x8*)&Bc[SWZ(rcb) * 8];
    }
    if (it < 15) {
      int k1 = (it + 1) * 32;
      float* An = sAf[cur ^ 1];
      unsigned short* Bn = sB[cur ^ 1];
      GLL(Af + aoff[0] + k1, An + acb[0] * 4);
      GLL(Af + aoff[1] + k1, An + acb[1] * 4);
      GLL(Af + aoff[2] + k1, An + acb[2] * 4);
      GLL(Af + aoff[3] + k1, An + acb[3] * 4);
      GLL(Bb + offB0 + k1, Bn + bcb0 * 8);
      GLL(Bb + offB1 + k1, Bn + bcb1 * 8);
    }
#pragma unroll
    for (int i = 0; i < 4; i++)
#pragma unroll
      for (int j = 0; j < 4; j++)
        acc[i][j] = __builtin_amdgcn_mfma_f32_16x16x32_bf16(ah[i], bh[j], acc[i][j], 0, 0, 0);
    __syncthreads();
  }

  int lq = lane >> 4;
#pragma unroll
  for (int i = 0; i < 4; i++) {
    int r0 = bm * 128 + wm + i * 16 + lq * 4;
#pragma unroll
    for (int j = 0; j < 4; j++) {
      int ccol = bn * 128 + wn + j * 16 + lr;
#pragma unroll
      for (int q = 0; q < 4; q++) {
        unsigned int myv = bf16_rne(acc[i][j][q]);
        unsigned int pv = __shfl_xor(myv, 1);
        int r = r0 + q;
        if (!(lr & 1) && r < Nn) {
          unsigned int word = myv | (pv << 16);
          *(unsigned int*)&Cb[(size_t)r * C1 + ccol] = word;
        }
      }
    }
  }
  int hh = bn * 2 + (wn >> 6);
  float aSj[4], aDj[4];
#pragma unroll
  for (int j = 0; j < 4; j++) {
    int cc = bn * 128 + wn + j * 16 + lr;
    aSj[j] = attS[cc]; aDj[j] = attD[cc];
  }
#pragma unroll
  for (int i = 0; i < 4; i++)
#pragma unroll
    for (int q = 0; q < 4; q++) {
      float s = acc[i][0][q] * aSj[0] + acc[i][1][q] * aSj[1]
              + acc[i][2][q] * aSj[2] + acc[i][3][q] * aSj[3];
      float dd = acc[i][0][q] * aDj[0] + acc[i][1][q] * aDj[1]
               + acc[i][2][q] * aDj[2] + acc[i][3][q] * aDj[3];
#pragma unroll
      for (int off = 1; off < 16; off <<= 1) {
        s += __shfl_xor(s, off);
        dd += __shfl_xor(dd, off);
      }
      int r = bm * 128 + wm + i * 16 + lq * 4 + q;
      if (lr == 0 && r < Nn) { as1[r * 8 + hh] = s; ad1[r * 8 + hh] = dd; }
    }
}

// --------------------------- CSR build by dst -------------------------------
__global__ __launch_bounds__(1024) void scan_kernel(
    const int* __restrict__ cnt, int* __restrict__ row)
{
  extern __shared__ int sm[];           // 1000 * 21 ints = 84 KB
  __shared__ int wsum[16];
  int t = threadIdx.x;

  for (int i = t; i < Nn; i += 1024) {
    int c = i / 20, o = i - c * 20;
    sm[c * 21 + o] = cnt[i];
  }
  __syncthreads();

  int v[20];
  int s = 0;
  if (t < 1000) {
    int base = t * 21;
#pragma unroll
    for (int j = 0; j < 20; j++) {
      int c = sm[base + j];
      v[j] = s;
      s += c;
    }
  }
  int lane = t & 63, w = t >> 6;
  int incl = s;
#pragma unroll
  for (int off = 1; off < 64; off <<= 1) {
    int o = __shfl_up(incl, off);
    if (lane >= off) incl += o;
  }
  if (lane == 63) wsum[w] = incl;
  __syncthreads();
  if (w == 0) {
    int ws = (lane < 16) ? wsum[lane] : 0;
#pragma unroll
    for (int off = 1; off < 16; off <<= 1) {
      int o = __shfl_up(ws, off);
      if (lane >= off) ws += o;
    }
    if (lane < 16) wsum[lane] = ws;
  }
  __syncthreads();
  int excl = ((w > 0) ? wsum[w - 1] : 0) + incl - s;
  if (t < 1000) {
    int base = t * 21;
#pragma unroll
    for (int j = 0; j < 20; j++) sm[base + j] = excl + v[j];
  }
  __syncthreads();
  for (int i = t; i < Nn; i += 1024) {
    int c = i / 20, o = i - c * 20;
    row[i] = sm[c * 21 + o];
  }
  if (t == 0) row[Nn] = EPn;
}

__global__ void scatter_kernel(const int* __restrict__ ei, const int* __restrict__ row,
                               int* __restrict__ cur, int* __restrict__ csr)
{
  int e4 = (blockIdx.x * 256 + threadIdx.x) * 4;
  if (e4 >= EPn) return;
  if (e4 < En) {
    int4 sv = *(const int4*)&ei[e4];
    int4 dv = *(const int4*)&ei[En + e4];
    int sa[4] = {sv.x, sv.y, sv.z, sv.w};
    int da[4] = {dv.x, dv.y, dv.z, dv.w};
#pragma unroll
    for (int j = 0; j < 4; j++) {
      int pos = row[da[j]] + atomicAdd(&cur[da[j]], 1);
      csr[pos] = sa[j];
    }
  } else {
#pragma unroll
    for (int j = 0; j < 4; j++) {
      int d = e4 - En + j;
      int pos = row[d] + atomicAdd(&cur[d], 1);
      csr[pos] = d;
    }
  }
}

// ----- layer-1 XCD-sliced softmax-gather + per-slice W2 partials ------------
// Block wgid: head h = wgid&7 -> XCD h (round-robin placement).  All blocks
// with the same h read ONLY h1b columns [64h,64h+64) = 2.5 MB < 4 MB per-XCD
// L2 => gathers become L2 hits.  Wave = one (dst, head): lanes split
// 2 edges x 32 channel-pairs (4B/lane, one 128B line per edge).  Single-pass
// unnormalized softmax (z per head is head-local -- exact).  Epilogue: relu
// (channel-local) then per-slice W2 partial contraction, accumulated into
// h2/as2/ad2 via atomicAdd (fp reassociation only; buffers pre-zeroed).
__global__ __launch_bounds__(256) void agg1_kernel(
    const int* __restrict__ row, const int* __restrict__ csr,
    const unsigned short* __restrict__ h1b, const float* __restrict__ as1,
    const float* __restrict__ adv, const float* __restrict__ b1,
    const unsigned short* __restrict__ W2b,
    const float* __restrict__ attS2, const float* __restrict__ attD2,
    float* __restrict__ h2, float* __restrict__ as2, float* __restrict__ ad2)
{
  int wgid = blockIdx.x;
  int h  = wgid & 7;                  // slice/head -> XCD h
  int dg = wgid >> 3;
  int t = threadIdx.x, lane = t & 63, w = t >> 6;
  int d = dg * 4 + w;                 // grid = (N/4)*8 exactly
  int beg = row[d], end = row[d + 1];
  int eo = lane >> 5;                 // edge parity this half-wave consumes
  int c2 = lane & 31;                 // channel pair within slice
  int ch = h * 64 + 2 * c2;
  float adH = adv[d * 8 + h];

  float a0 = 0.f, a1 = 0.f, z = 0.f;
  for (int e = beg + eo; e < end; e += 2) {
    int s = csr[e];                   // broadcast within half-wave
    float v = as1[s * 8 + h] + adH;
    v = (v >= 0.f) ? v : NEG * v;
    float p = __expf(v);              // unnormalized; z divides at the end
    z += p;
    unsigned int u = *(const unsigned int*)&h1b[(size_t)s * C1 + ch];
    a0 = fmaf(p, __uint_as_float(u << 16), a0);
    a1 = fmaf(p, __uint_as_float(u & 0xffff0000u), a1);
  }
  a0 += __shfl_xor(a0, 32);
  a1 += __shfl_xor(a1, 32);
  z  += __shfl_xor(z, 32);

  float rz = 1.f / z;                 // deg >= 1 (self-loop)
  float o0 = fmaf(a0, rz, b1[ch]);     o0 = o0 > 0.f ? o0 : 0.f;
  float o1 = fmaf(a1, rz, b1[ch + 1]); o1 = o1 > 0.f ? o1 : 0.f;

  // per-slice W2 partials: pj = sum_{c in slice} relu[c] * W2[j][c]
  float s2 = 0.f, d2 = 0.f, myj = 0.f;
#pragma unroll
  for (int j = 0; j < OUT_CH; j++) {
    unsigned int wu = *(const unsigned int*)&W2b[j * 512 + ch];
    float pj = o0 * __uint_as_float(wu << 16)
             + o1 * __uint_as_float(wu & 0xffff0000u);
    pj += __shfl_xor(pj, 1);
    pj += __shfl_xor(pj, 2);
    pj += __shfl_xor(pj, 4);
    pj += __shfl_xor(pj, 8);
    pj += __shfl_xor(pj, 16);
    if (c2 == j) myj = pj;
    s2 = fmaf(pj, attS2[j], s2);
    d2 = fmaf(pj, attD2[j], d2);
  }
  if (eo == 0) {
    if (c2 < OUT_CH) atomicAdd(&h2[(size_t)d * OUT_CH + c2], myj);
    else if (c2 == 16) atomicAdd(&as2[d], s2);
    else if (c2 == 17) atomicAdd(&ad2[d], d2);
  }
}

// ------- layer-2 single-pass softmax-gather (one wave per dst), +b2 ---------
__global__ __launch_bounds__(256) void agg2_kernel(
    const int* __restrict__ row, const int* __restrict__ csr,
    const float* __restrict__ h2, const float* __restrict__ as2,
    const float* __restrict__ ad2, const float* __restrict__ b2,
    float* __restrict__ out)
{
  int wave = threadIdx.x >> 6, lane = threadIdx.x & 63;
  int d = blockIdx.x * 4 + wave;   // grid = N/4 exactly
  int beg = row[d], end = row[d + 1];
  float add = ad2[d];

  int c = lane & 15;
  float acc = 0.f, z = 0.f;
  for (int e = beg + (lane >> 4); e < end; e += 4) {
    int s = csr[e];
    float v = as2[s] + add;
    v = (v >= 0.f) ? v : NEG * v;
    float p = __expf(v);
    z += p;
    acc = fmaf(p, h2[(size_t)s * 16 + c], acc);
  }
  acc += __shfl_xor(acc, 16);
  acc += __shfl_xor(acc, 32);
  z += __shfl_xor(z, 16);
  z += __shfl_xor(z, 32);
  if (lane < 16) out[(size_t)d * 16 + lane] = acc / z + b2[lane];
}

extern "C" void kernel_launch(void* const* d_in, const int* in_sizes, int n_in,
                              void* d_out, int out_size, void* d_ws, size_t ws_size,
                              hipStream_t stream)
{
  const float* x    = (const float*)d_in[0];
  const int*   ei   = (const int*)d_in[1];
  const float* W1   = (const float*)d_in[2];
  const float* asv1 = (const float*)d_in[3];
  const float* adv1 = (const float*)d_in[4];
  const float* b1   = (const float*)d_in[5];
  const float* W2   = (const float*)d_in[6];
  const float* asv2 = (const float*)d_in[7];
  const float* adv2 = (const float*)d_in[8];
  const float* b2   = (const float*)d_in[9];
  float* out = (float*)d_out;

  // workspace layout (16B-aligned regions), ~26 MB
  unsigned short* h1b = (unsigned short*)d_ws;                // N*512 bf16
  unsigned short* w_b = h1b + (size_t)Nn * C1;                // 512*512 bf16
  unsigned short* w2b = w_b + (size_t)C1 * IN_CH;             // 16*512 bf16
  float* as1   = (float*)(w2b + (size_t)OUT_CH * C1);         // N*8
  float* ad1   = as1 + (size_t)Nn * H1n;                      // N*8
  float* h2    = ad1 + (size_t)Nn * H1n;                      // N*16 (zeroed below)
  float* as2   = h2 + (size_t)Nn * OUT_CH;                    // N    (zeroed below)
  float* ad2   = as2 + Nn;                                    // N    (zeroed below)
  int* cnt  = (int*)(ad2 + Nn);                               // N    (zeroed below)
  int* cur  = cnt + Nn;                                       // N    (zeroed below)
  int* rowp = cur + Nn;                                       // N+1
  int* csr  = rowp + Nn + 1;                                  // E+N

  hipMemsetAsync(h2, 0, (size_t)Nn * 20 * sizeof(float), stream);  // h2..cur

  cvtwh_kernel<<<(NW8 + NW28 + NH4 + 255) / 256, 256, 0, stream>>>(
      W1, w_b, W2, w2b, ei, cnt);

  gemm1_mfma<<<640, 256, 0, stream>>>(x, w_b, asv1, adv1, h1b, as1, ad1);

  scan_kernel<<<1, 1024, 1000 * 21 * sizeof(int), stream>>>(cnt, rowp);
  scatter_kernel<<<(EPn / 4 + 255) / 256, 256, 0, stream>>>(ei, rowp, cur, csr);
  agg1_kernel<<<(Nn / 4) * 8, 256, 0, stream>>>(rowp, csr, h1b, as1, ad1, b1,
                                                w2b, asv2, adv2, h2, as2, ad2);
  agg2_kernel<<<Nn / 4, 256, 0, stream>>>(rowp, csr, h2, as2, ad2, b2, out);
}

// Round 23
// 235.664 us; speedup vs baseline: 1.1459x; 1.1459x over previous
//
#include <hip/hip_runtime.h>

#define Nn     20000
#define IN_CH  512
#define C1     512      // H1*HID
#define H1n    8
#define HIDn   64
#define OUT_CH 16
#define En     320000
#define EPn    340000   // E + N self-loops
#define NEG    0.2f

typedef __attribute__((ext_vector_type(8))) short bf16x8;
typedef __attribute__((ext_vector_type(4))) float f32x4;

// ---------------- fp32 -> bf16 helpers (RNE) --------------------------------
__device__ inline unsigned short bf16_rne(float f) {
  unsigned int u = __float_as_uint(f);
  return (unsigned short)((u + 0x7fffu + ((u >> 16) & 1u)) >> 16);
}
__device__ inline float bf16_f(unsigned short u) {
  return __uint_as_float(((unsigned int)u) << 16);
}

// packed f32x8 -> bf16x8 via hardware cvt_pk (RNE)
__device__ inline bf16x8 pack8(float4 f0, float4 f1) {
  unsigned int r0, r1, r2, r3;
  asm("v_cvt_pk_bf16_f32 %0, %1, %2" : "=v"(r0) : "v"(f0.x), "v"(f0.y));
  asm("v_cvt_pk_bf16_f32 %0, %1, %2" : "=v"(r1) : "v"(f0.z), "v"(f0.w));
  asm("v_cvt_pk_bf16_f32 %0, %1, %2" : "=v"(r2) : "v"(f1.x), "v"(f1.y));
  asm("v_cvt_pk_bf16_f32 %0, %1, %2" : "=v"(r3) : "v"(f1.z), "v"(f1.w));
  union { unsigned int u[4]; bf16x8 v; } un;
  un.u[0] = r0; un.u[1] = r1; un.u[2] = r2; un.u[3] = r3;
  return un.v;
}

// W1, W2 -> bf16 + edge histogram, one launch (cnt pre-zeroed by memset)
#define NW8  (C1 * IN_CH / 8)
#define NW28 (OUT_CH * C1 / 8)
#define NH4  (EPn / 4)
__global__ __launch_bounds__(256) void cvtwh_kernel(
    const float* __restrict__ W1, unsigned short* __restrict__ w1b,
    const float* __restrict__ W2, unsigned short* __restrict__ w2b,
    const int* __restrict__ ei, int* __restrict__ cnt)
{
  int i = blockIdx.x * 256 + threadIdx.x;
  const float* in; unsigned short* ob; int idx;
  if (i < NW8) { in = W1; ob = w1b; idx = i; }
  else if (i < NW8 + NW28) { in = W2; ob = w2b; idx = i - NW8; }
  else if (i < NW8 + NW28 + NH4) {
    int e4 = (i - NW8 - NW28) * 4;      // En, EPn divisible by 4
    if (e4 < En) {
      int4 dv = *(const int4*)&ei[En + e4];
      atomicAdd(&cnt[dv.x], 1); atomicAdd(&cnt[dv.y], 1);
      atomicAdd(&cnt[dv.z], 1); atomicAdd(&cnt[dv.w], 1);
    } else {
      int d = e4 - En;
      atomicAdd(&cnt[d], 1);     atomicAdd(&cnt[d + 1], 1);
      atomicAdd(&cnt[d + 2], 1); atomicAdd(&cnt[d + 3], 1);
    }
    return;
  } else return;
  float4 f0 = ((const float4*)in)[idx * 2];
  float4 f1 = ((const float4*)in)[idx * 2 + 1];
  float f[8] = {f0.x, f0.y, f0.z, f0.w, f1.x, f1.y, f1.z, f1.w};
  unsigned short h[8];
#pragma unroll
  for (int j = 0; j < 8; j++) h[j] = bf16_rne(f[j]);
  ushort4 hv0 = {h[0], h[1], h[2], h[3]}, hv1 = {h[4], h[5], h[6], h[7]};
  ((ushort4*)ob)[idx * 2] = hv0; ((ushort4*)ob)[idx * 2 + 1] = hv1;
}

// ------ GEMM1: h1b[N,512](bf16) = x(f32) @ W1b^T + fused logits -------------
// Round-19 form: 128x128 tile, double-buffered LDS, XCD-aware mapping.
#define GLL(gp, lp) __builtin_amdgcn_global_load_lds( \
    (const __attribute__((address_space(1))) void*)(gp), \
    (__attribute__((address_space(3))) void*)(lp), 16, 0, 0)

#define SWZ(c)  ((c) ^ (((c) >> 3) & 3))   // bf16 rows: 4 chunks/row
#define SWZA(c) ((c) ^ (((c) >> 3) & 7))   // f32 rows: 8 chunks/row

__global__ __launch_bounds__(256, 3) void gemm1_mfma(
    const float* __restrict__ Af, const unsigned short* __restrict__ Bb,
    const float* __restrict__ attS, const float* __restrict__ attD,
    unsigned short* __restrict__ Cb, float* __restrict__ as1, float* __restrict__ ad1)
{
  __shared__ float sAf[2][128 * 32];          // 2 x 16 KB
  __shared__ unsigned short sB[2][128 * 32];  // 2 x 8 KB
  int t = threadIdx.x;
  int wgid = blockIdx.x;
  int bm = (wgid & 7) + 8 * (wgid >> 5);
  int bn = (wgid >> 3) & 3;
  if (bm >= 157) return;               // 12 pad blocks
  int lane = t & 63, w = t >> 6;

  int acb[4]; size_t aoff[4];
#pragma unroll
  for (int q = 0; q < 4; q++) {
    int slot = w * 256 + q * 64 + lane;
    acb[q] = w * 256 + q * 64;             // wave-uniform LDS base chunk
    int cs = SWZA(slot);
    int ra = bm * 128 + (cs >> 3); if (ra > Nn - 1) ra = Nn - 1;
    aoff[q] = (size_t)ra * IN_CH + (cs & 7) * 4;
  }
  int slot0 = w * 128 + lane, slot1 = slot0 + 64;
  int bcb0 = w * 128, bcb1 = w * 128 + 64;
  int cs0 = SWZ(slot0), cs1 = SWZ(slot1);
  int br0 = bn * 128 + (cs0 >> 2);
  int br1 = bn * 128 + (cs1 >> 2);
  size_t offB0 = (size_t)br0 * IN_CH + (cs0 & 3) * 8;
  size_t offB1 = (size_t)br1 * IN_CH + (cs1 & 3) * 8;

  int wm = (w >> 1) * 64, wn = (w & 1) * 64;
  int lr = lane & 15, kb = lane >> 4;

  f32x4 acc[4][4] = {};

  GLL(Af + aoff[0], sAf[0] + acb[0] * 4);
  GLL(Af + aoff[1], sAf[0] + acb[1] * 4);
  GLL(Af + aoff[2], sAf[0] + acb[2] * 4);
  GLL(Af + aoff[3], sAf[0] + acb[3] * 4);
  GLL(Bb + offB0, sB[0] + bcb0 * 8);
  GLL(Bb + offB1, sB[0] + bcb1 * 8);
  __syncthreads();

#pragma unroll 2
  for (int it = 0; it < 16; it++) {
    int cur = it & 1;
    const float* Ac = sAf[cur];
    const unsigned short* Bc = sB[cur];
    bf16x8 ah[4], bh[4];
#pragma unroll
    for (int i = 0; i < 4; i++) {
      int c0 = (wm + i * 16 + lr) * 8 + kb * 2;
      float4 f0 = *(const float4*)&Ac[SWZA(c0) * 4];
      float4 f1 = *(const float4*)&Ac[SWZA(c0 + 1) * 4];
      ah[i] = pack8(f0, f1);
      int rcb = (wn + i * 16 + lr) * 4 + kb;
      bh[i] = *(const bf16x8*)&Bc[SWZ(rcb) * 8];
    }
    if (it < 15) {
      int k1 = (it + 1) * 32;
      float* An = sAf[cur ^ 1];
      unsigned short* Bn = sB[cur ^ 1];
      GLL(Af + aoff[0] + k1, An + acb[0] * 4);
      GLL(Af + aoff[1] + k1, An + acb[1] * 4);
      GLL(Af + aoff[2] + k1, An + acb[2] * 4);
      GLL(Af + aoff[3] + k1, An + acb[3] * 4);
      GLL(Bb + offB0 + k1, Bn + bcb0 * 8);
      GLL(Bb + offB1 + k1, Bn + bcb1 * 8);
    }
#pragma unroll
    for (int i = 0; i < 4; i++)
#pragma unroll
      for (int j = 0; j < 4; j++)
        acc[i][j] = __builtin_amdgcn_mfma_f32_16x16x32_bf16(ah[i], bh[j], acc[i][j], 0, 0, 0);
    __syncthreads();
  }

  int lq = lane >> 4;
#pragma unroll
  for (int i = 0; i < 4; i++) {
    int r0 = bm * 128 + wm + i * 16 + lq * 4;
#pragma unroll
    for (int j = 0; j < 4; j++) {
      int ccol = bn * 128 + wn + j * 16 + lr;
#pragma unroll
      for (int q = 0; q < 4; q++) {
        unsigned int myv = bf16_rne(acc[i][j][q]);
        unsigned int pv = __shfl_xor(myv, 1);
        int r = r0 + q;
        if (!(lr & 1) && r < Nn) {
          unsigned int word = myv | (pv << 16);
          *(unsigned int*)&Cb[(size_t)r * C1 + ccol] = word;
        }
      }
    }
  }
  int hh = bn * 2 + (wn >> 6);
  float aSj[4], aDj[4];
#pragma unroll
  for (int j = 0; j < 4; j++) {
    int cc = bn * 128 + wn + j * 16 + lr;
    aSj[j] = attS[cc]; aDj[j] = attD[cc];
  }
#pragma unroll
  for (int i = 0; i < 4; i++)
#pragma unroll
    for (int q = 0; q < 4; q++) {
      float s = acc[i][0][q] * aSj[0] + acc[i][1][q] * aSj[1]
              + acc[i][2][q] * aSj[2] + acc[i][3][q] * aSj[3];
      float dd = acc[i][0][q] * aDj[0] + acc[i][1][q] * aDj[1]
               + acc[i][2][q] * aDj[2] + acc[i][3][q] * aDj[3];
#pragma unroll
      for (int off = 1; off < 16; off <<= 1) {
        s += __shfl_xor(s, off);
        dd += __shfl_xor(dd, off);
      }
      int r = bm * 128 + wm + i * 16 + lq * 4 + q;
      if (lr == 0 && r < Nn) { as1[r * 8 + hh] = s; ad1[r * 8 + hh] = dd; }
    }
}

// --------------------------- CSR build by dst -------------------------------
__global__ __launch_bounds__(1024) void scan_kernel(
    const int* __restrict__ cnt, int* __restrict__ row)
{
  extern __shared__ int sm[];           // 1000 * 21 ints = 84 KB
  __shared__ int wsum[16];
  int t = threadIdx.x;

  for (int i = t; i < Nn; i += 1024) {
    int c = i / 20, o = i - c * 20;
    sm[c * 21 + o] = cnt[i];
  }
  __syncthreads();

  int v[20];
  int s = 0;
  if (t < 1000) {
    int base = t * 21;
#pragma unroll
    for (int j = 0; j < 20; j++) {
      int c = sm[base + j];
      v[j] = s;
      s += c;
    }
  }
  int lane = t & 63, w = t >> 6;
  int incl = s;
#pragma unroll
  for (int off = 1; off < 64; off <<= 1) {
    int o = __shfl_up(incl, off);
    if (lane >= off) incl += o;
  }
  if (lane == 63) wsum[w] = incl;
  __syncthreads();
  if (w == 0) {
    int ws = (lane < 16) ? wsum[lane] : 0;
#pragma unroll
    for (int off = 1; off < 16; off <<= 1) {
      int o = __shfl_up(ws, off);
      if (lane >= off) ws += o;
    }
    if (lane < 16) wsum[lane] = ws;
  }
  __syncthreads();
  int excl = ((w > 0) ? wsum[w - 1] : 0) + incl - s;
  if (t < 1000) {
    int base = t * 21;
#pragma unroll
    for (int j = 0; j < 20; j++) sm[base + j] = excl + v[j];
  }
  __syncthreads();
  for (int i = t; i < Nn; i += 1024) {
    int c = i / 20, o = i - c * 20;
    row[i] = sm[c * 21 + o];
  }
  if (t == 0) row[Nn] = EPn;
}

__global__ void scatter_kernel(const int* __restrict__ ei, const int* __restrict__ row,
                               int* __restrict__ cur, int* __restrict__ csr)
{
  int e4 = (blockIdx.x * 256 + threadIdx.x) * 4;
  if (e4 >= EPn) return;
  if (e4 < En) {
    int4 sv = *(const int4*)&ei[e4];
    int4 dv = *(const int4*)&ei[En + e4];
    int sa[4] = {sv.x, sv.y, sv.z, sv.w};
    int da[4] = {dv.x, dv.y, dv.z, dv.w};
#pragma unroll
    for (int j = 0; j < 4; j++) {
      int pos = row[da[j]] + atomicAdd(&cur[da[j]], 1);
      csr[pos] = sa[j];
    }
  } else {
#pragma unroll
    for (int j = 0; j < 4; j++) {
      int d = e4 - En + j;
      int pos = row[d] + atomicAdd(&cur[d], 1);
      csr[pos] = d;
    }
  }
}

// ----- layer-1 XCD-sliced softmax-gather, edge-group layout -----------------
// Block wgid: head h = wgid&7 -> XCD h (round-robin).  Same-h blocks read
// ONLY h1b columns [64h,64h+64) = 2.5 MB < 4 MB per-XCD L2 => L2-hit gathers
// (round-22 FETCH: 21 MB, confirmed).  Wave = one (dst, head); lanes =
// 8 edge-groups (eg=lane>>3, edges beg+eg, +8, ...) x 8 channel-octets
// (cl=lane&7, 16B/lane) -> 8 edges in flight, 128B slice per edge,
// deg/8 iterations.  Reduce a/z across edge-groups (xor 8/16/32).
// Epilogue: relu slice + W2 partial contraction (reduce over cl, xor 1/2/4),
// atomicAdd into h2/as2/ad2 (pre-zeroed; fp reassociation only).
__global__ __launch_bounds__(256) void agg1_kernel(
    const int* __restrict__ row, const int* __restrict__ csr,
    const unsigned short* __restrict__ h1b, const float* __restrict__ as1,
    const float* __restrict__ adv, const float* __restrict__ b1,
    const unsigned short* __restrict__ W2b,
    const float* __restrict__ attS2, const float* __restrict__ attD2,
    float* __restrict__ h2, float* __restrict__ as2, float* __restrict__ ad2)
{
  int wgid = blockIdx.x;
  int h  = wgid & 7;                  // slice/head -> XCD h
  int dg = wgid >> 3;
  int t = threadIdx.x, lane = t & 63, w = t >> 6;
  int d = dg * 4 + w;                 // grid = (N/4)*8 exactly
  int beg = row[d], end = row[d + 1];
  int eg = lane >> 3;                 // edge group (8 edges in flight)
  int cl = lane & 7;                  // channel octet within slice
  int ch = h * 64 + cl * 8;
  float adH = adv[d * 8 + h];

  float a0 = 0.f, a1 = 0.f, a2 = 0.f, a3 = 0.f;
  float a4 = 0.f, a5 = 0.f, a6 = 0.f, a7 = 0.f;
  float z = 0.f;
  for (int e = beg + eg; e < end; e += 8) {
    int s = csr[e];                   // broadcast within 8-lane group
    float v = as1[s * 8 + h] + adH;
    v = (v >= 0.f) ? v : NEG * v;
    float p = __expf(v);              // unnormalized; z divides at the end
    z += p;
    uint4 u = *(const uint4*)&h1b[(size_t)s * C1 + ch];
    a0 = fmaf(p, __uint_as_float(u.x << 16), a0);
    a1 = fmaf(p, __uint_as_float(u.x & 0xffff0000u), a1);
    a2 = fmaf(p, __uint_as_float(u.y << 16), a2);
    a3 = fmaf(p, __uint_as_float(u.y & 0xffff0000u), a3);
    a4 = fmaf(p, __uint_as_float(u.z << 16), a4);
    a5 = fmaf(p, __uint_as_float(u.z & 0xffff0000u), a5);
    a6 = fmaf(p, __uint_as_float(u.w << 16), a6);
    a7 = fmaf(p, __uint_as_float(u.w & 0xffff0000u), a7);
  }
  // reduce across the 8 edge groups (cl fixed)
#pragma unroll
  for (int off = 8; off < 64; off <<= 1) {
    a0 += __shfl_xor(a0, off); a1 += __shfl_xor(a1, off);
    a2 += __shfl_xor(a2, off); a3 += __shfl_xor(a3, off);
    a4 += __shfl_xor(a4, off); a5 += __shfl_xor(a5, off);
    a6 += __shfl_xor(a6, off); a7 += __shfl_xor(a7, off);
    z  += __shfl_xor(z, off);
  }

  float rz = 1.f / z;                 // deg >= 1 (self-loop)
  float o0 = fmaf(a0, rz, b1[ch + 0]); o0 = o0 > 0.f ? o0 : 0.f;
  float o1 = fmaf(a1, rz, b1[ch + 1]); o1 = o1 > 0.f ? o1 : 0.f;
  float o2 = fmaf(a2, rz, b1[ch + 2]); o2 = o2 > 0.f ? o2 : 0.f;
  float o3 = fmaf(a3, rz, b1[ch + 3]); o3 = o3 > 0.f ? o3 : 0.f;
  float o4 = fmaf(a4, rz, b1[ch + 4]); o4 = o4 > 0.f ? o4 : 0.f;
  float o5 = fmaf(a5, rz, b1[ch + 5]); o5 = o5 > 0.f ? o5 : 0.f;
  float o6 = fmaf(a6, rz, b1[ch + 6]); o6 = o6 > 0.f ? o6 : 0.f;
  float o7 = fmaf(a7, rz, b1[ch + 7]); o7 = o7 > 0.f ? o7 : 0.f;

  // per-slice W2 partials: pj = sum_{c in slice} relu[c] * W2[j][c]
  float s2 = 0.f, d2 = 0.f, myj = 0.f;
#pragma unroll
  for (int j = 0; j < OUT_CH; j++) {
    bf16x8 wv = *(const bf16x8*)&W2b[j * 512 + ch];
    float pj = o0 * bf16_f((unsigned short)wv[0]) + o1 * bf16_f((unsigned short)wv[1])
             + o2 * bf16_f((unsigned short)wv[2]) + o3 * bf16_f((unsigned short)wv[3])
             + o4 * bf16_f((unsigned short)wv[4]) + o5 * bf16_f((unsigned short)wv[5])
             + o6 * bf16_f((unsigned short)wv[6]) + o7 * bf16_f((unsigned short)wv[7]);
    pj += __shfl_xor(pj, 1);
    pj += __shfl_xor(pj, 2);
    pj += __shfl_xor(pj, 4);          // slice total in every lane
    if (lane == j) myj = pj;
    s2 = fmaf(pj, attS2[j], s2);
    d2 = fmaf(pj, attD2[j], d2);
  }
  if (lane < OUT_CH) atomicAdd(&h2[(size_t)d * OUT_CH + lane], myj);
  else if (lane == 16) atomicAdd(&as2[d], s2);
  else if (lane == 17) atomicAdd(&ad2[d], d2);
}

// ------- layer-2 single-pass softmax-gather (one wave per dst), +b2 ---------
__global__ __launch_bounds__(256) void agg2_kernel(
    const int* __restrict__ row, const int* __restrict__ csr,
    const float* __restrict__ h2, const float* __restrict__ as2,
    const float* __restrict__ ad2, const float* __restrict__ b2,
    float* __restrict__ out)
{
  int wave = threadIdx.x >> 6, lane = threadIdx.x & 63;
  int d = blockIdx.x * 4 + wave;   // grid = N/4 exactly
  int beg = row[d], end = row[d + 1];
  float add = ad2[d];

  int c = lane & 15;
  float acc = 0.f, z = 0.f;
  for (int e = beg + (lane >> 4); e < end; e += 4) {
    int s = csr[e];
    float v = as2[s] + add;
    v = (v >= 0.f) ? v : NEG * v;
    float p = __expf(v);
    z += p;
    acc = fmaf(p, h2[(size_t)s * 16 + c], acc);
  }
  acc += __shfl_xor(acc, 16);
  acc += __shfl_xor(acc, 32);
  z += __shfl_xor(z, 16);
  z += __shfl_xor(z, 32);
  if (lane < 16) out[(size_t)d * 16 + lane] = acc / z + b2[lane];
}

extern "C" void kernel_launch(void* const* d_in, const int* in_sizes, int n_in,
                              void* d_out, int out_size, void* d_ws, size_t ws_size,
                              hipStream_t stream)
{
  const float* x    = (const float*)d_in[0];
  const int*   ei   = (const int*)d_in[1];
  const float* W1   = (const float*)d_in[2];
  const float* asv1 = (const float*)d_in[3];
  const float* adv1 = (const float*)d_in[4];
  const float* b1   = (const float*)d_in[5];
  const float* W2   = (const float*)d_in[6];
  const float* asv2 = (const float*)d_in[7];
  const float* adv2 = (const float*)d_in[8];
  const float* b2   = (const float*)d_in[9];
  float* out = (float*)d_out;

  // workspace layout (16B-aligned regions), ~26 MB
  unsigned short* h1b = (unsigned short*)d_ws;                // N*512 bf16
  unsigned short* w_b = h1b + (size_t)Nn * C1;                // 512*512 bf16
  unsigned short* w2b = w_b + (size_t)C1 * IN_CH;             // 16*512 bf16
  float* as1   = (float*)(w2b + (size_t)OUT_CH * C1);         // N*8
  float* ad1   = as1 + (size_t)Nn * H1n;                      // N*8
  float* h2    = ad1 + (size_t)Nn * H1n;                      // N*16 (zeroed below)
  float* as2   = h2 + (size_t)Nn * OUT_CH;                    // N    (zeroed below)
  float* ad2   = as2 + Nn;                                    // N    (zeroed below)
  int* cnt  = (int*)(ad2 + Nn);                               // N    (zeroed below)
  int* cur  = cnt + Nn;                                       // N    (zeroed below)
  int* rowp = cur + Nn;                                       // N+1
  int* csr  = rowp + Nn + 1;                                  // E+N

  hipMemsetAsync(h2, 0, (size_t)Nn * 20 * sizeof(float), stream);  // h2..cur

  cvtwh_kernel<<<(NW8 + NW28 + NH4 + 255) / 256, 256, 0, stream>>>(
      W1, w_b, W2, w2b, ei, cnt);

  gemm1_mfma<<<640, 256, 0, stream>>>(x, w_b, asv1, adv1, h1b, as1, ad1);

  scan_kernel<<<1, 1024, 1000 * 21 * sizeof(int), stream>>>(cnt, rowp);
  scatter_kernel<<<(EPn / 4 + 255) / 256, 256, 0, stream>>>(ei, rowp, cur, csr);
  agg1_kernel<<<(Nn / 4) * 8, 256, 0, stream>>>(rowp, csr, h1b, as1, ad1, b1,
                                                w2b, asv2, adv2, h2, as2, ad2);
  agg2_kernel<<<Nn / 4, 256, 0, stream>>>(rowp, csr, h2, as2, ad2, b2, out);
}

// Round 24
// 164.660 us; speedup vs baseline: 1.6400x; 1.4312x over previous
//
#include <hip/hip_runtime.h>

#define Nn     20000
#define IN_CH  512
#define C1     512      // H1*HID
#define H1n    8
#define HIDn   64
#define OUT_CH 16
#define En     320000
#define EPn    340000   // E + N self-loops
#define NEG    0.2f

typedef __attribute__((ext_vector_type(8))) short bf16x8;
typedef __attribute__((ext_vector_type(4))) float f32x4;

// ---------------- fp32 -> bf16 helpers (RNE) --------------------------------
__device__ inline unsigned short bf16_rne(float f) {
  unsigned int u = __float_as_uint(f);
  return (unsigned short)((u + 0x7fffu + ((u >> 16) & 1u)) >> 16);
}
__device__ inline float bf16_f(unsigned short u) {
  return __uint_as_float(((unsigned int)u) << 16);
}

// packed f32x8 -> bf16x8 via hardware cvt_pk (RNE)
__device__ inline bf16x8 pack8(float4 f0, float4 f1) {
  unsigned int r0, r1, r2, r3;
  asm("v_cvt_pk_bf16_f32 %0, %1, %2" : "=v"(r0) : "v"(f0.x), "v"(f0.y));
  asm("v_cvt_pk_bf16_f32 %0, %1, %2" : "=v"(r1) : "v"(f0.z), "v"(f0.w));
  asm("v_cvt_pk_bf16_f32 %0, %1, %2" : "=v"(r2) : "v"(f1.x), "v"(f1.y));
  asm("v_cvt_pk_bf16_f32 %0, %1, %2" : "=v"(r3) : "v"(f1.z), "v"(f1.w));
  union { unsigned int u[4]; bf16x8 v; } un;
  un.u[0] = r0; un.u[1] = r1; un.u[2] = r2; un.u[3] = r3;
  return un.v;
}

// W1, W2 -> bf16 + edge histogram, one launch (cnt pre-zeroed by memset)
#define NW8  (C1 * IN_CH / 8)
#define NW28 (OUT_CH * C1 / 8)
#define NH4  (EPn / 4)
__global__ __launch_bounds__(256) void cvtwh_kernel(
    const float* __restrict__ W1, unsigned short* __restrict__ w1b,
    const float* __restrict__ W2, unsigned short* __restrict__ w2b,
    const int* __restrict__ ei, int* __restrict__ cnt)
{
  int i = blockIdx.x * 256 + threadIdx.x;
  const float* in; unsigned short* ob; int idx;
  if (i < NW8) { in = W1; ob = w1b; idx = i; }
  else if (i < NW8 + NW28) { in = W2; ob = w2b; idx = i - NW8; }
  else if (i < NW8 + NW28 + NH4) {
    int e4 = (i - NW8 - NW28) * 4;      // En, EPn divisible by 4
    if (e4 < En) {
      int4 dv = *(const int4*)&ei[En + e4];
      atomicAdd(&cnt[dv.x], 1); atomicAdd(&cnt[dv.y], 1);
      atomicAdd(&cnt[dv.z], 1); atomicAdd(&cnt[dv.w], 1);
    } else {
      int d = e4 - En;
      atomicAdd(&cnt[d], 1);     atomicAdd(&cnt[d + 1], 1);
      atomicAdd(&cnt[d + 2], 1); atomicAdd(&cnt[d + 3], 1);
    }
    return;
  } else return;
  float4 f0 = ((const float4*)in)[idx * 2];
  float4 f1 = ((const float4*)in)[idx * 2 + 1];
  float f[8] = {f0.x, f0.y, f0.z, f0.w, f1.x, f1.y, f1.z, f1.w};
  unsigned short h[8];
#pragma unroll
  for (int j = 0; j < 8; j++) h[j] = bf16_rne(f[j]);
  ushort4 hv0 = {h[0], h[1], h[2], h[3]}, hv1 = {h[4], h[5], h[6], h[7]};
  ((ushort4*)ob)[idx * 2] = hv0; ((ushort4*)ob)[idx * 2 + 1] = hv1;
}

// ------ GEMM1: h1b[N,512](bf16) = x(f32) @ W1b^T + fused logits -------------
// 128x128 tile, double-buffered LDS, XCD-aware mapping.
#define GLL(gp, lp) __builtin_amdgcn_global_load_lds( \
    (const __attribute__((address_space(1))) void*)(gp), \
    (__attribute__((address_space(3))) void*)(lp), 16, 0, 0)

#define SWZ(c)  ((c) ^ (((c) >> 3) & 3))   // bf16 rows: 4 chunks/row
#define SWZA(c) ((c) ^ (((c) >> 3) & 7))   // f32 rows: 8 chunks/row

__global__ __launch_bounds__(256, 3) void gemm1_mfma(
    const float* __restrict__ Af, const unsigned short* __restrict__ Bb,
    const float* __restrict__ attS, const float* __restrict__ attD,
    unsigned short* __restrict__ Cb, float* __restrict__ as1, float* __restrict__ ad1)
{
  __shared__ float sAf[2][128 * 32];          // 2 x 16 KB
  __shared__ unsigned short sB[2][128 * 32];  // 2 x 8 KB
  int t = threadIdx.x;
  int wgid = blockIdx.x;
  int bm = (wgid & 7) + 8 * (wgid >> 5);
  int bn = (wgid >> 3) & 3;
  if (bm >= 157) return;               // 12 pad blocks
  int lane = t & 63, w = t >> 6;

  int acb[4]; size_t aoff[4];
#pragma unroll
  for (int q = 0; q < 4; q++) {
    int slot = w * 256 + q * 64 + lane;
    acb[q] = w * 256 + q * 64;             // wave-uniform LDS base chunk
    int cs = SWZA(slot);
    int ra = bm * 128 + (cs >> 3); if (ra > Nn - 1) ra = Nn - 1;
    aoff[q] = (size_t)ra * IN_CH + (cs & 7) * 4;
  }
  int slot0 = w * 128 + lane, slot1 = slot0 + 64;
  int bcb0 = w * 128, bcb1 = w * 128 + 64;
  int cs0 = SWZ(slot0), cs1 = SWZ(slot1);
  int br0 = bn * 128 + (cs0 >> 2);
  int br1 = bn * 128 + (cs1 >> 2);
  size_t offB0 = (size_t)br0 * IN_CH + (cs0 & 3) * 8;
  size_t offB1 = (size_t)br1 * IN_CH + (cs1 & 3) * 8;

  int wm = (w >> 1) * 64, wn = (w & 1) * 64;
  int lr = lane & 15, kb = lane >> 4;

  f32x4 acc[4][4] = {};

  GLL(Af + aoff[0], sAf[0] + acb[0] * 4);
  GLL(Af + aoff[1], sAf[0] + acb[1] * 4);
  GLL(Af + aoff[2], sAf[0] + acb[2] * 4);
  GLL(Af + aoff[3], sAf[0] + acb[3] * 4);
  GLL(Bb + offB0, sB[0] + bcb0 * 8);
  GLL(Bb + offB1, sB[0] + bcb1 * 8);
  __syncthreads();

#pragma unroll 2
  for (int it = 0; it < 16; it++) {
    int cur = it & 1;
    const float* Ac = sAf[cur];
    const unsigned short* Bc = sB[cur];
    bf16x8 ah[4], bh[4];
#pragma unroll
    for (int i = 0; i < 4; i++) {
      int c0 = (wm + i * 16 + lr) * 8 + kb * 2;
      float4 f0 = *(const float4*)&Ac[SWZA(c0) * 4];
      float4 f1 = *(const float4*)&Ac[SWZA(c0 + 1) * 4];
      ah[i] = pack8(f0, f1);
      int rcb = (wn + i * 16 + lr) * 4 + kb;
      bh[i] = *(const bf16x8*)&Bc[SWZ(rcb) * 8];
    }
    if (it < 15) {
      int k1 = (it + 1) * 32;
      float* An = sAf[cur ^ 1];
      unsigned short* Bn = sB[cur ^ 1];
      GLL(Af + aoff[0] + k1, An + acb[0] * 4);
      GLL(Af + aoff[1] + k1, An + acb[1] * 4);
      GLL(Af + aoff[2] + k1, An + acb[2] * 4);
      GLL(Af + aoff[3] + k1, An + acb[3] * 4);
      GLL(Bb + offB0 + k1, Bn + bcb0 * 8);
      GLL(Bb + offB1 + k1, Bn + bcb1 * 8);
    }
#pragma unroll
    for (int i = 0; i < 4; i++)
#pragma unroll
      for (int j = 0; j < 4; j++)
        acc[i][j] = __builtin_amdgcn_mfma_f32_16x16x32_bf16(ah[i], bh[j], acc[i][j], 0, 0, 0);
    __syncthreads();
  }

  int lq = lane >> 4;
#pragma unroll
  for (int i = 0; i < 4; i++) {
    int r0 = bm * 128 + wm + i * 16 + lq * 4;
#pragma unroll
    for (int j = 0; j < 4; j++) {
      int ccol = bn * 128 + wn + j * 16 + lr;
#pragma unroll
      for (int q = 0; q < 4; q++) {
        unsigned int myv = bf16_rne(acc[i][j][q]);
        unsigned int pv = __shfl_xor(myv, 1);
        int r = r0 + q;
        if (!(lr & 1) && r < Nn) {
          unsigned int word = myv | (pv << 16);
          *(unsigned int*)&Cb[(size_t)r * C1 + ccol] = word;
        }
      }
    }
  }
  int hh = bn * 2 + (wn >> 6);
  float aSj[4], aDj[4];
#pragma unroll
  for (int j = 0; j < 4; j++) {
    int cc = bn * 128 + wn + j * 16 + lr;
    aSj[j] = attS[cc]; aDj[j] = attD[cc];
  }
#pragma unroll
  for (int i = 0; i < 4; i++)
#pragma unroll
    for (int q = 0; q < 4; q++) {
      float s = acc[i][0][q] * aSj[0] + acc[i][1][q] * aSj[1]
              + acc[i][2][q] * aSj[2] + acc[i][3][q] * aSj[3];
      float dd = acc[i][0][q] * aDj[0] + acc[i][1][q] * aDj[1]
               + acc[i][2][q] * aDj[2] + acc[i][3][q] * aDj[3];
#pragma unroll
      for (int off = 1; off < 16; off <<= 1) {
        s += __shfl_xor(s, off);
        dd += __shfl_xor(dd, off);
      }
      int r = bm * 128 + wm + i * 16 + lq * 4 + q;
      if (lr == 0 && r < Nn) { as1[r * 8 + hh] = s; ad1[r * 8 + hh] = dd; }
    }
}

// --------------------------- CSR build by dst -------------------------------
__global__ __launch_bounds__(1024) void scan_kernel(
    const int* __restrict__ cnt, int* __restrict__ row)
{
  extern __shared__ int sm[];           // 1000 * 21 ints = 84 KB
  __shared__ int wsum[16];
  int t = threadIdx.x;

  for (int i = t; i < Nn; i += 1024) {
    int c = i / 20, o = i - c * 20;
    sm[c * 21 + o] = cnt[i];
  }
  __syncthreads();

  int v[20];
  int s = 0;
  if (t < 1000) {
    int base = t * 21;
#pragma unroll
    for (int j = 0; j < 20; j++) {
      int c = sm[base + j];
      v[j] = s;
      s += c;
    }
  }
  int lane = t & 63, w = t >> 6;
  int incl = s;
#pragma unroll
  for (int off = 1; off < 64; off <<= 1) {
    int o = __shfl_up(incl, off);
    if (lane >= off) incl += o;
  }
  if (lane == 63) wsum[w] = incl;
  __syncthreads();
  if (w == 0) {
    int ws = (lane < 16) ? wsum[lane] : 0;
#pragma unroll
    for (int off = 1; off < 16; off <<= 1) {
      int o = __shfl_up(ws, off);
      if (lane >= off) ws += o;
    }
    if (lane < 16) wsum[lane] = ws;
  }
  __syncthreads();
  int excl = ((w > 0) ? wsum[w - 1] : 0) + incl - s;
  if (t < 1000) {
    int base = t * 21;
#pragma unroll
    for (int j = 0; j < 20; j++) sm[base + j] = excl + v[j];
  }
  __syncthreads();
  for (int i = t; i < Nn; i += 1024) {
    int c = i / 20, o = i - c * 20;
    row[i] = sm[c * 21 + o];
  }
  if (t == 0) row[Nn] = EPn;
}

__global__ void scatter_kernel(const int* __restrict__ ei, const int* __restrict__ row,
                               int* __restrict__ cur, int* __restrict__ csr)
{
  int e4 = (blockIdx.x * 256 + threadIdx.x) * 4;
  if (e4 >= EPn) return;
  if (e4 < En) {
    int4 sv = *(const int4*)&ei[e4];
    int4 dv = *(const int4*)&ei[En + e4];
    int sa[4] = {sv.x, sv.y, sv.z, sv.w};
    int da[4] = {dv.x, dv.y, dv.z, dv.w};
#pragma unroll
    for (int j = 0; j < 4; j++) {
      int pos = row[da[j]] + atomicAdd(&cur[da[j]], 1);
      csr[pos] = sa[j];
    }
  } else {
#pragma unroll
    for (int j = 0; j < 4; j++) {
      int d = e4 - En + j;
      int pos = row[d] + atomicAdd(&cur[d], 1);
      csr[pos] = d;
    }
  }
}

// ----- layer-1 XCD-sliced softmax-gather -> relu1b slice store --------------
// Block wgid: head h = wgid&7 -> XCD h (round-robin).  Same-h blocks read
// ONLY h1b columns [64h,64h+64) = 2.5 MB < 4 MB per-XCD L2 (round-22/23
// FETCH 21 MB confirmed).  Wave = one (dst, head); lanes = 8 edge-groups x
// 8 channel-octets (16B/lane).  After the cross-edge-group reduce, lanes 0-7
// hold the full relu slice -> ONE 128B coalesced bf16 store.  Layer-2
// transform moved back to the tiny l2_mfma kernel (no per-wave W2 epilogue,
// which was 100%-VALU-bound at 160K waves in round 23).
__global__ __launch_bounds__(256) void agg1_kernel(
    const int* __restrict__ row, const int* __restrict__ csr,
    const unsigned short* __restrict__ h1b, const float* __restrict__ as1,
    const float* __restrict__ adv, const float* __restrict__ b1,
    unsigned short* __restrict__ relu1b)
{
  int wgid = blockIdx.x;
  int h  = wgid & 7;                  // slice/head -> XCD h
  int dg = wgid >> 3;
  int t = threadIdx.x, lane = t & 63, w = t >> 6;
  int d = dg * 4 + w;                 // grid = (N/4)*8 exactly
  int beg = row[d], end = row[d + 1];
  int eg = lane >> 3;                 // edge group (8 edges in flight)
  int cl = lane & 7;                  // channel octet within slice
  int ch = h * 64 + cl * 8;
  float adH = adv[d * 8 + h];

  float a0 = 0.f, a1 = 0.f, a2 = 0.f, a3 = 0.f;
  float a4 = 0.f, a5 = 0.f, a6 = 0.f, a7 = 0.f;
  float z = 0.f;
  for (int e = beg + eg; e < end; e += 8) {
    int s = csr[e];                   // broadcast within 8-lane group
    float v = as1[s * 8 + h] + adH;
    v = (v >= 0.f) ? v : NEG * v;
    float p = __expf(v);              // unnormalized; z divides at the end
    z += p;
    uint4 u = *(const uint4*)&h1b[(size_t)s * C1 + ch];
    a0 = fmaf(p, __uint_as_float(u.x << 16), a0);
    a1 = fmaf(p, __uint_as_float(u.x & 0xffff0000u), a1);
    a2 = fmaf(p, __uint_as_float(u.y << 16), a2);
    a3 = fmaf(p, __uint_as_float(u.y & 0xffff0000u), a3);
    a4 = fmaf(p, __uint_as_float(u.z << 16), a4);
    a5 = fmaf(p, __uint_as_float(u.z & 0xffff0000u), a5);
    a6 = fmaf(p, __uint_as_float(u.w << 16), a6);
    a7 = fmaf(p, __uint_as_float(u.w & 0xffff0000u), a7);
  }
  // reduce across the 8 edge groups (cl fixed)
#pragma unroll
  for (int off = 8; off < 64; off <<= 1) {
    a0 += __shfl_xor(a0, off); a1 += __shfl_xor(a1, off);
    a2 += __shfl_xor(a2, off); a3 += __shfl_xor(a3, off);
    a4 += __shfl_xor(a4, off); a5 += __shfl_xor(a5, off);
    a6 += __shfl_xor(a6, off); a7 += __shfl_xor(a7, off);
    z  += __shfl_xor(z, off);
  }

  if (lane < 8) {                     // lanes 0-7 hold the slice
    float rz = 1.f / z;               // deg >= 1 (self-loop)
    float o0 = fmaf(a0, rz, b1[ch + 0]); o0 = o0 > 0.f ? o0 : 0.f;
    float o1 = fmaf(a1, rz, b1[ch + 1]); o1 = o1 > 0.f ? o1 : 0.f;
    float o2 = fmaf(a2, rz, b1[ch + 2]); o2 = o2 > 0.f ? o2 : 0.f;
    float o3 = fmaf(a3, rz, b1[ch + 3]); o3 = o3 > 0.f ? o3 : 0.f;
    float o4 = fmaf(a4, rz, b1[ch + 4]); o4 = o4 > 0.f ? o4 : 0.f;
    float o5 = fmaf(a5, rz, b1[ch + 5]); o5 = o5 > 0.f ? o5 : 0.f;
    float o6 = fmaf(a6, rz, b1[ch + 6]); o6 = o6 > 0.f ? o6 : 0.f;
    float o7 = fmaf(a7, rz, b1[ch + 7]); o7 = o7 > 0.f ? o7 : 0.f;
    float4 f0 = {o0, o1, o2, o3}, f1 = {o4, o5, o6, o7};
    *(bf16x8*)&relu1b[(size_t)d * C1 + ch] = pack8(f0, f1);
  }
}

// --------- layer-2 transform (MFMA): h2[N,16] = relu1b @ W2^T ---------------
// One 16-row tile per wave; B-frags (W2b) preloaded; 16 MFMA over K=512.
__global__ __launch_bounds__(256) void l2_mfma(
    const unsigned short* __restrict__ Xb, const unsigned short* __restrict__ W2b,
    const float* __restrict__ att_s, const float* __restrict__ att_d,
    float* __restrict__ h2, float* __restrict__ as2, float* __restrict__ ad2)
{
  int w = threadIdx.x >> 6, lane = threadIdx.x & 63;
  int tile = blockIdx.x * 4 + w;
  if (tile >= Nn / 16) return;          // 1250 tiles
  int n0 = tile * 16;
  int lr = lane & 15, kb = lane >> 4;

  bf16x8 bf[16];
#pragma unroll
  for (int k0 = 0; k0 < 16; k0++)
    bf[k0] = *(const bf16x8*)&W2b[lr * 512 + kb * 8 + k0 * 32];

  f32x4 acc = {0.f, 0.f, 0.f, 0.f};
#pragma unroll
  for (int k0 = 0; k0 < 16; k0++) {
    bf16x8 af = *(const bf16x8*)&Xb[(size_t)(n0 + lr) * 512 + kb * 8 + k0 * 32];
    acc = __builtin_amdgcn_mfma_f32_16x16x32_bf16(af, bf[k0], acc, 0, 0, 0);
  }

  float aS = att_s[lr], aD = att_d[lr];   // col = lr
#pragma unroll
  for (int r = 0; r < 4; r++) {
    int n = n0 + kb * 4 + r;
    h2[(size_t)n * 16 + lr] = acc[r];
    float sv = acc[r] * aS, dv = acc[r] * aD;
#pragma unroll
    for (int off = 1; off < 16; off <<= 1) {
      sv += __shfl_xor(sv, off);
      dv += __shfl_xor(dv, off);
    }
    if (lr == 0) { as2[n] = sv; ad2[n] = dv; }
  }
}

// ------- layer-2 single-pass softmax-gather (one wave per dst), +b2 ---------
__global__ __launch_bounds__(256) void agg2_kernel(
    const int* __restrict__ row, const int* __restrict__ csr,
    const float* __restrict__ h2, const float* __restrict__ as2,
    const float* __restrict__ ad2, const float* __restrict__ b2,
    float* __restrict__ out)
{
  int wave = threadIdx.x >> 6, lane = threadIdx.x & 63;
  int d = blockIdx.x * 4 + wave;   // grid = N/4 exactly
  int beg = row[d], end = row[d + 1];
  float add = ad2[d];

  int c = lane & 15;
  float acc = 0.f, z = 0.f;
  for (int e = beg + (lane >> 4); e < end; e += 4) {
    int s = csr[e];
    float v = as2[s] + add;
    v = (v >= 0.f) ? v : NEG * v;
    float p = __expf(v);
    z += p;
    acc = fmaf(p, h2[(size_t)s * 16 + c], acc);
  }
  acc += __shfl_xor(acc, 16);
  acc += __shfl_xor(acc, 32);
  z += __shfl_xor(z, 16);
  z += __shfl_xor(z, 32);
  if (lane < 16) out[(size_t)d * 16 + lane] = acc / z + b2[lane];
}

extern "C" void kernel_launch(void* const* d_in, const int* in_sizes, int n_in,
                              void* d_out, int out_size, void* d_ws, size_t ws_size,
                              hipStream_t stream)
{
  const float* x    = (const float*)d_in[0];
  const int*   ei   = (const int*)d_in[1];
  const float* W1   = (const float*)d_in[2];
  const float* asv1 = (const float*)d_in[3];
  const float* adv1 = (const float*)d_in[4];
  const float* b1   = (const float*)d_in[5];
  const float* W2   = (const float*)d_in[6];
  const float* asv2 = (const float*)d_in[7];
  const float* adv2 = (const float*)d_in[8];
  const float* b2   = (const float*)d_in[9];
  float* out = (float*)d_out;

  // workspace layout (16B-aligned regions), ~46 MB
  unsigned short* h1b    = (unsigned short*)d_ws;             // N*512 bf16
  unsigned short* relu1b = h1b + (size_t)Nn * C1;             // N*512 bf16
  unsigned short* w_b    = relu1b + (size_t)Nn * C1;          // 512*512 bf16
  unsigned short* w2b    = w_b + (size_t)C1 * IN_CH;          // 16*512 bf16
  float* as1   = (float*)(w2b + (size_t)OUT_CH * C1);         // N*8
  float* ad1   = as1 + (size_t)Nn * H1n;                      // N*8
  float* h2    = ad1 + (size_t)Nn * H1n;                      // N*16
  float* as2   = h2 + (size_t)Nn * OUT_CH;                    // N
  float* ad2   = as2 + Nn;                                    // N
  int* cnt  = (int*)(ad2 + Nn);                               // N  (cnt|cur zeroed)
  int* cur  = cnt + Nn;                                       // N
  int* rowp = cur + Nn;                                       // N+1
  int* csr  = rowp + Nn + 1;                                  // E+N

  hipMemsetAsync(cnt, 0, 2 * Nn * sizeof(int), stream);

  cvtwh_kernel<<<(NW8 + NW28 + NH4 + 255) / 256, 256, 0, stream>>>(
      W1, w_b, W2, w2b, ei, cnt);

  gemm1_mfma<<<640, 256, 0, stream>>>(x, w_b, asv1, adv1, h1b, as1, ad1);

  scan_kernel<<<1, 1024, 1000 * 21 * sizeof(int), stream>>>(cnt, rowp);
  scatter_kernel<<<(EPn / 4 + 255) / 256, 256, 0, stream>>>(ei, rowp, cur, csr);
  agg1_kernel<<<(Nn / 4) * 8, 256, 0, stream>>>(rowp, csr, h1b, as1, ad1, b1, relu1b);
  l2_mfma<<<(Nn / 16 + 3) / 4, 256, 0, stream>>>(relu1b, w2b, asv2, adv2, h2, as2, ad2);
  agg2_kernel<<<Nn / 4, 256, 0, stream>>>(rowp, csr, h2, as2, ad2, b2, out);
}

// Round 25
// 140.771 us; speedup vs baseline: 1.9183x; 1.1697x over previous
//
#include <hip/hip_runtime.h>

#define Nn     20000
#define IN_CH  512
#define C1     512      // H1*HID
#define H1n    8
#define HIDn   64
#define OUT_CH 16
#define En     320000
#define EPn    340000   // E + N self-loops
#define NEG    0.2f

typedef __attribute__((ext_vector_type(8))) short bf16x8;
typedef __attribute__((ext_vector_type(4))) float f32x4;

// ---------------- fp32 -> bf16 helpers (RNE) --------------------------------
__device__ inline unsigned short bf16_rne(float f) {
  unsigned int u = __float_as_uint(f);
  return (unsigned short)((u + 0x7fffu + ((u >> 16) & 1u)) >> 16);
}
__device__ inline float bf16_f(unsigned short u) {
  return __uint_as_float(((unsigned int)u) << 16);
}

// packed f32x8 -> bf16x8 via hardware cvt_pk (RNE)
__device__ inline bf16x8 pack8(float4 f0, float4 f1) {
  unsigned int r0, r1, r2, r3;
  asm("v_cvt_pk_bf16_f32 %0, %1, %2" : "=v"(r0) : "v"(f0.x), "v"(f0.y));
  asm("v_cvt_pk_bf16_f32 %0, %1, %2" : "=v"(r1) : "v"(f0.z), "v"(f0.w));
  asm("v_cvt_pk_bf16_f32 %0, %1, %2" : "=v"(r2) : "v"(f1.x), "v"(f1.y));
  asm("v_cvt_pk_bf16_f32 %0, %1, %2" : "=v"(r3) : "v"(f1.z), "v"(f1.w));
  union { unsigned int u[4]; bf16x8 v; } un;
  un.u[0] = r0; un.u[1] = r1; un.u[2] = r2; un.u[3] = r3;
  return un.v;
}

// W1, W2 -> bf16 + edge histogram, one launch (cnt pre-zeroed by memset)
#define NW8  (C1 * IN_CH / 8)
#define NW28 (OUT_CH * C1 / 8)
#define NH4  (EPn / 4)
__global__ __launch_bounds__(256) void cvtwh_kernel(
    const float* __restrict__ W1, unsigned short* __restrict__ w1b,
    const float* __restrict__ W2, unsigned short* __restrict__ w2b,
    const int* __restrict__ ei, int* __restrict__ cnt)
{
  int i = blockIdx.x * 256 + threadIdx.x;
  const float* in; unsigned short* ob; int idx;
  if (i < NW8) { in = W1; ob = w1b; idx = i; }
  else if (i < NW8 + NW28) { in = W2; ob = w2b; idx = i - NW8; }
  else if (i < NW8 + NW28 + NH4) {
    int e4 = (i - NW8 - NW28) * 4;      // En, EPn divisible by 4
    if (e4 < En) {
      int4 dv = *(const int4*)&ei[En + e4];
      atomicAdd(&cnt[dv.x], 1); atomicAdd(&cnt[dv.y], 1);
      atomicAdd(&cnt[dv.z], 1); atomicAdd(&cnt[dv.w], 1);
    } else {
      int d = e4 - En;
      atomicAdd(&cnt[d], 1);     atomicAdd(&cnt[d + 1], 1);
      atomicAdd(&cnt[d + 2], 1); atomicAdd(&cnt[d + 3], 1);
    }
    return;
  } else return;
  float4 f0 = ((const float4*)in)[idx * 2];
  float4 f1 = ((const float4*)in)[idx * 2 + 1];
  float f[8] = {f0.x, f0.y, f0.z, f0.w, f1.x, f1.y, f1.z, f1.w};
  unsigned short h[8];
#pragma unroll
  for (int j = 0; j < 8; j++) h[j] = bf16_rne(f[j]);
  ushort4 hv0 = {h[0], h[1], h[2], h[3]}, hv1 = {h[4], h[5], h[6], h[7]};
  ((ushort4*)ob)[idx * 2] = hv0; ((ushort4*)ob)[idx * 2 + 1] = hv1;
}

// ------ GEMM1: h1b[N,512](bf16) = x(f32) @ W1b^T + fused logits -------------
// 128x128 tile, double-buffered LDS (issue next tile before MFMA, one barrier
// per K-step), XCD-aware block mapping (4 bn-sharers of an A-tile on the same
// XCD => A fetched from HBM once).
#define GLL(gp, lp) __builtin_amdgcn_global_load_lds( \
    (const __attribute__((address_space(1))) void*)(gp), \
    (__attribute__((address_space(3))) void*)(lp), 16, 0, 0)

#define SWZ(c)  ((c) ^ (((c) >> 3) & 3))   // bf16 rows: 4 chunks/row
#define SWZA(c) ((c) ^ (((c) >> 3) & 7))   // f32 rows: 8 chunks/row

__global__ __launch_bounds__(256, 3) void gemm1_mfma(
    const float* __restrict__ Af, const unsigned short* __restrict__ Bb,
    const float* __restrict__ attS, const float* __restrict__ attD,
    unsigned short* __restrict__ Cb, float* __restrict__ as1, float* __restrict__ ad1)
{
  __shared__ float sAf[2][128 * 32];          // 2 x 16 KB
  __shared__ unsigned short sB[2][128 * 32];  // 2 x 8 KB  (48 KB total)
  int t = threadIdx.x;
  int wgid = blockIdx.x;
  int bm = (wgid & 7) + 8 * (wgid >> 5);
  int bn = (wgid >> 3) & 3;
  if (bm >= 157) return;               // 12 pad blocks
  int lane = t & 63, w = t >> 6;

  int acb[4]; size_t aoff[4];
#pragma unroll
  for (int q = 0; q < 4; q++) {
    int slot = w * 256 + q * 64 + lane;
    acb[q] = w * 256 + q * 64;             // wave-uniform LDS base chunk
    int cs = SWZA(slot);
    int ra = bm * 128 + (cs >> 3); if (ra > Nn - 1) ra = Nn - 1;
    aoff[q] = (size_t)ra * IN_CH + (cs & 7) * 4;
  }
  int slot0 = w * 128 + lane, slot1 = slot0 + 64;
  int bcb0 = w * 128, bcb1 = w * 128 + 64;
  int cs0 = SWZ(slot0), cs1 = SWZ(slot1);
  int br0 = bn * 128 + (cs0 >> 2);
  int br1 = bn * 128 + (cs1 >> 2);
  size_t offB0 = (size_t)br0 * IN_CH + (cs0 & 3) * 8;
  size_t offB1 = (size_t)br1 * IN_CH + (cs1 & 3) * 8;

  int wm = (w >> 1) * 64, wn = (w & 1) * 64;
  int lr = lane & 15, kb = lane >> 4;

  f32x4 acc[4][4] = {};

  // prologue: stage K-tile 0 into buffer 0
  GLL(Af + aoff[0], sAf[0] + acb[0] * 4);
  GLL(Af + aoff[1], sAf[0] + acb[1] * 4);
  GLL(Af + aoff[2], sAf[0] + acb[2] * 4);
  GLL(Af + aoff[3], sAf[0] + acb[3] * 4);
  GLL(Bb + offB0, sB[0] + bcb0 * 8);
  GLL(Bb + offB1, sB[0] + bcb1 * 8);
  __syncthreads();

#pragma unroll 2
  for (int it = 0; it < 16; it++) {
    int cur = it & 1;
    const float* Ac = sAf[cur];
    const unsigned short* Bc = sB[cur];
    bf16x8 ah[4], bh[4];
#pragma unroll
    for (int i = 0; i < 4; i++) {
      int c0 = (wm + i * 16 + lr) * 8 + kb * 2;
      float4 f0 = *(const float4*)&Ac[SWZA(c0) * 4];
      float4 f1 = *(const float4*)&Ac[SWZA(c0 + 1) * 4];
      ah[i] = pack8(f0, f1);
      int rcb = (wn + i * 16 + lr) * 4 + kb;
      bh[i] = *(const bf16x8*)&Bc[SWZ(rcb) * 8];
    }
    if (it < 15) {                       // issue next tile (no wait)
      int k1 = (it + 1) * 32;
      float* An = sAf[cur ^ 1];
      unsigned short* Bn = sB[cur ^ 1];
      GLL(Af + aoff[0] + k1, An + acb[0] * 4);
      GLL(Af + aoff[1] + k1, An + acb[1] * 4);
      GLL(Af + aoff[2] + k1, An + acb[2] * 4);
      GLL(Af + aoff[3] + k1, An + acb[3] * 4);
      GLL(Bb + offB0 + k1, Bn + bcb0 * 8);
      GLL(Bb + offB1 + k1, Bn + bcb1 * 8);
    }
#pragma unroll
    for (int i = 0; i < 4; i++)
#pragma unroll
      for (int j = 0; j < 4; j++)
        acc[i][j] = __builtin_amdgcn_mfma_f32_16x16x32_bf16(ah[i], bh[j], acc[i][j], 0, 0, 0);
    __syncthreads();                     // vmcnt drain: next buffer ready
  }

  int lq = lane >> 4;
  // C store: pack col pairs (lr, lr^1) via shfl -> even lanes store 4B words
#pragma unroll
  for (int i = 0; i < 4; i++) {
    int r0 = bm * 128 + wm + i * 16 + lq * 4;
#pragma unroll
    for (int j = 0; j < 4; j++) {
      int ccol = bn * 128 + wn + j * 16 + lr;   // even lanes: cols ccol, ccol+1
#pragma unroll
      for (int q = 0; q < 4; q++) {
        unsigned int myv = bf16_rne(acc[i][j][q]);
        unsigned int pv = __shfl_xor(myv, 1);
        int r = r0 + q;
        if (!(lr & 1) && r < Nn) {
          unsigned int word = myv | (pv << 16);
          *(unsigned int*)&Cb[(size_t)r * C1 + ccol] = word;
        }
      }
    }
  }
  // fused logits: this wave's cols are head hh
  int hh = bn * 2 + (wn >> 6);
  float aSj[4], aDj[4];
#pragma unroll
  for (int j = 0; j < 4; j++) {
    int cc = bn * 128 + wn + j * 16 + lr;
    aSj[j] = attS[cc]; aDj[j] = attD[cc];
  }
#pragma unroll
  for (int i = 0; i < 4; i++)
#pragma unroll
    for (int q = 0; q < 4; q++) {
      float s = acc[i][0][q] * aSj[0] + acc[i][1][q] * aSj[1]
              + acc[i][2][q] * aSj[2] + acc[i][3][q] * aSj[3];
      float dd = acc[i][0][q] * aDj[0] + acc[i][1][q] * aDj[1]
               + acc[i][2][q] * aDj[2] + acc[i][3][q] * aDj[3];
#pragma unroll
      for (int off = 1; off < 16; off <<= 1) {
        s += __shfl_xor(s, off);
        dd += __shfl_xor(dd, off);
      }
      int r = bm * 128 + wm + i * 16 + lq * 4 + q;
      if (lr == 0 && r < Nn) { as1[r * 8 + hh] = s; ad1[r * 8 + hh] = dd; }
    }
}

// --------------------------- CSR build by dst -------------------------------
// Coalesced LDS-staged scan: strided coalesced load of cnt into padded LDS
// (stride-21 chunks, conflict-free), per-thread 20-elem scan, block shuffle
// scan, writeback via LDS, coalesced store.
__global__ __launch_bounds__(1024) void scan_kernel(
    const int* __restrict__ cnt, int* __restrict__ row)
{
  extern __shared__ int sm[];           // 1000 * 21 ints = 84 KB
  __shared__ int wsum[16];
  int t = threadIdx.x;

  for (int i = t; i < Nn; i += 1024) {  // coalesced load
    int c = i / 20, o = i - c * 20;
    sm[c * 21 + o] = cnt[i];
  }
  __syncthreads();

  int v[20];
  int s = 0;
  if (t < 1000) {
    int base = t * 21;
#pragma unroll
    for (int j = 0; j < 20; j++) {
      int c = sm[base + j];
      v[j] = s;
      s += c;
    }
  }
  int lane = t & 63, w = t >> 6;
  int incl = s;
#pragma unroll
  for (int off = 1; off < 64; off <<= 1) {
    int o = __shfl_up(incl, off);
    if (lane >= off) incl += o;
  }
  if (lane == 63) wsum[w] = incl;
  __syncthreads();
  if (w == 0) {
    int ws = (lane < 16) ? wsum[lane] : 0;
#pragma unroll
    for (int off = 1; off < 16; off <<= 1) {
      int o = __shfl_up(ws, off);
      if (lane >= off) ws += o;
    }
    if (lane < 16) wsum[lane] = ws;
  }
  __syncthreads();
  int excl = ((w > 0) ? wsum[w - 1] : 0) + incl - s;
  if (t < 1000) {
    int base = t * 21;
#pragma unroll
    for (int j = 0; j < 20; j++) sm[base + j] = excl + v[j];
  }
  __syncthreads();
  for (int i = t; i < Nn; i += 1024) {  // coalesced store
    int c = i / 20, o = i - c * 20;
    row[i] = sm[c * 21 + o];
  }
  if (t == 0) row[Nn] = EPn;
}

__global__ void scatter_kernel(const int* __restrict__ ei, const int* __restrict__ row,
                               int* __restrict__ cur, int* __restrict__ csr)
{
  int e4 = (blockIdx.x * 256 + threadIdx.x) * 4;
  if (e4 >= EPn) return;
  if (e4 < En) {
    int4 sv = *(const int4*)&ei[e4];
    int4 dv = *(const int4*)&ei[En + e4];
    int sa[4] = {sv.x, sv.y, sv.z, sv.w};
    int da[4] = {dv.x, dv.y, dv.z, dv.w};
#pragma unroll
    for (int j = 0; j < 4; j++) {
      int pos = row[da[j]] + atomicAdd(&cur[da[j]], 1);
      csr[pos] = sa[j];
    }
  } else {
#pragma unroll
    for (int j = 0; j < 4; j++) {
      int d = e4 - En + j;
      int pos = row[d] + atomicAdd(&cur[d], 1);
      csr[pos] = d;
    }
  }
}

// ----- layer-1 softmax-gather + FUSED layer-2 transform ---------------------
// Single-pass unnormalized softmax (z-division after aggregation); wave pair
// splits edges by parity; one barrier.  The combined relu row (f32, in regs)
// is contracted with W2 read directly from GLOBAL (16 KB, L2/L1-resident).
// Gather loop: unroll 4 (36 VGPR, 4 gathers in flight -- unroll 8 serializes
// loads and regresses 28%, round-15 lesson).
__global__ __launch_bounds__(256, 6) void agg1_kernel(
    const int* __restrict__ row, const int* __restrict__ csr,
    const unsigned short* __restrict__ h1b, const float* __restrict__ as1,
    const float* __restrict__ adv, const float* __restrict__ b1,
    const unsigned short* __restrict__ W2b,
    const float* __restrict__ attS2, const float* __restrict__ attD2,
    float* __restrict__ h2, float* __restrict__ as2, float* __restrict__ ad2)
{
  __shared__ float part[2][64 * 9];

  int t = threadIdx.x, lane = t & 63, w = t >> 6;
  int pr = w >> 1;                    // dst pair slot within block
  int p  = w & 1;                     // edge parity this wave consumes
  int d = blockIdx.x * 2 + pr;        // grid = N/2 exactly
  int beg = row[d], end = row[d + 1];
  int deg = end - beg;
  int hq = lane >> 3;                 // this lane's head (8 ch/lane)
  size_t chb = (size_t)8 * lane;
  float adH = adv[d * 8 + hq];

  float a0 = 0.f, a1 = 0.f, a2 = 0.f, a3 = 0.f;
  float a4 = 0.f, a5 = 0.f, a6 = 0.f, a7 = 0.f;
  float z = 0.f;
  int nj = (deg - p + 1) >> 1;        // edges with index parity p
#pragma unroll 4
  for (int j = 0; j < nj; j++) {
    int e = beg + p + 2 * j;
    int s = csr[e];                   // wave-uniform broadcast load
    float v = as1[s * 8 + hq] + adH;
    v = (v >= 0.f) ? v : NEG * v;
    float pp = __expf(v);             // unnormalized; z divides at the end
    z += pp;
    uint4 u = *(const uint4*)&h1b[(size_t)s * C1 + chb];
    a0 = fmaf(pp, __uint_as_float(u.x << 16), a0);
    a1 = fmaf(pp, __uint_as_float(u.x & 0xffff0000u), a1);
    a2 = fmaf(pp, __uint_as_float(u.y << 16), a2);
    a3 = fmaf(pp, __uint_as_float(u.y & 0xffff0000u), a3);
    a4 = fmaf(pp, __uint_as_float(u.z << 16), a4);
    a5 = fmaf(pp, __uint_as_float(u.z & 0xffff0000u), a5);
    a6 = fmaf(pp, __uint_as_float(u.w << 16), a6);
    a7 = fmaf(pp, __uint_as_float(u.w & 0xffff0000u), a7);
  }

  if (p == 1) {                       // write-once partial slice
    float* ps = &part[pr][lane * 9];
    ps[0] = a0; ps[1] = a1; ps[2] = a2; ps[3] = a3;
    ps[4] = a4; ps[5] = a5; ps[6] = a6; ps[7] = a7; ps[8] = z;
  }
  __syncthreads();                    // partials ready
  if (p == 0) {
    const float* ps = &part[pr][lane * 9];
    a0 += ps[0]; a1 += ps[1]; a2 += ps[2]; a3 += ps[3];
    a4 += ps[4]; a5 += ps[5]; a6 += ps[6]; a7 += ps[7]; z += ps[8];
    float rz = 1.f / z;
    float4 b0 = *(const float4*)&b1[chb];
    float4 b4 = *(const float4*)&b1[chb + 4];
    float o0 = fmaf(a0, rz, b0.x); o0 = o0 > 0.f ? o0 : 0.f;
    float o1 = fmaf(a1, rz, b0.y); o1 = o1 > 0.f ? o1 : 0.f;
    float o2 = fmaf(a2, rz, b0.z); o2 = o2 > 0.f ? o2 : 0.f;
    float o3 = fmaf(a3, rz, b0.w); o3 = o3 > 0.f ? o3 : 0.f;
    float o4 = fmaf(a4, rz, b4.x); o4 = o4 > 0.f ? o4 : 0.f;
    float o5 = fmaf(a5, rz, b4.y); o5 = o5 > 0.f ? o5 : 0.f;
    float o6 = fmaf(a6, rz, b4.z); o6 = o6 > 0.f ? o6 : 0.f;
    float o7 = fmaf(a7, rz, b4.w); o7 = o7 > 0.f ? o7 : 0.f;

    // fused layer-2: h2[d][j] = sum_c relu[c] * W2[j][c]  (W2 from global)
    float myh2 = 0.f, s2 = 0.f, d2 = 0.f;
#pragma unroll
    for (int j = 0; j < OUT_CH; j++) {
      bf16x8 wv = *(const bf16x8*)&W2b[j * 512 + chb];
      float pj = o0 * bf16_f((unsigned short)wv[0]) + o1 * bf16_f((unsigned short)wv[1])
               + o2 * bf16_f((unsigned short)wv[2]) + o3 * bf16_f((unsigned short)wv[3])
               + o4 * bf16_f((unsigned short)wv[4]) + o5 * bf16_f((unsigned short)wv[5])
               + o6 * bf16_f((unsigned short)wv[6]) + o7 * bf16_f((unsigned short)wv[7]);
#pragma unroll
      for (int off = 1; off < 64; off <<= 1) pj += __shfl_xor(pj, off);
      if (lane == j) myh2 = pj;
      s2 = fmaf(pj, attS2[j], s2);
      d2 = fmaf(pj, attD2[j], d2);
    }
    if (lane < OUT_CH) h2[(size_t)d * OUT_CH + lane] = myh2;
    if (lane == 0) { as2[d] = s2; ad2[d] = d2; }
  }
}

// ------- layer-2 single-pass softmax-gather (one wave per dst), +b2 ---------
__global__ __launch_bounds__(256) void agg2_kernel(
    const int* __restrict__ row, const int* __restrict__ csr,
    const float* __restrict__ h2, const float* __restrict__ as2,
    const float* __restrict__ ad2, const float* __restrict__ b2,
    float* __restrict__ out)
{
  int wave = threadIdx.x >> 6, lane = threadIdx.x & 63;
  int d = blockIdx.x * 4 + wave;   // grid = N/4 exactly
  int beg = row[d], end = row[d + 1];
  float add = ad2[d];

  int c = lane & 15;
  float acc = 0.f, z = 0.f;
  for (int e = beg + (lane >> 4); e < end; e += 4) {
    int s = csr[e];
    float v = as2[s] + add;
    v = (v >= 0.f) ? v : NEG * v;
    float p = __expf(v);
    z += p;
    acc = fmaf(p, h2[(size_t)s * 16 + c], acc);
  }
  acc += __shfl_xor(acc, 16);
  acc += __shfl_xor(acc, 32);
  z += __shfl_xor(z, 16);
  z += __shfl_xor(z, 32);
  if (lane < 16) out[(size_t)d * 16 + lane] = acc / z + b2[lane];
}

extern "C" void kernel_launch(void* const* d_in, const int* in_sizes, int n_in,
                              void* d_out, int out_size, void* d_ws, size_t ws_size,
                              hipStream_t stream)
{
  const float* x    = (const float*)d_in[0];
  const int*   ei   = (const int*)d_in[1];
  const float* W1   = (const float*)d_in[2];
  const float* asv1 = (const float*)d_in[3];
  const float* adv1 = (const float*)d_in[4];
  const float* b1   = (const float*)d_in[5];
  const float* W2   = (const float*)d_in[6];
  const float* asv2 = (const float*)d_in[7];
  const float* adv2 = (const float*)d_in[8];
  const float* b2   = (const float*)d_in[9];
  float* out = (float*)d_out;

  // workspace layout (16B-aligned regions), ~26 MB
  unsigned short* h1b = (unsigned short*)d_ws;                // N*512 bf16
  unsigned short* w_b = h1b + (size_t)Nn * C1;                // 512*512 bf16
  unsigned short* w2b = w_b + (size_t)C1 * IN_CH;             // 16*512 bf16
  float* as1   = (float*)(w2b + (size_t)OUT_CH * C1);         // N*8
  float* ad1   = as1 + (size_t)Nn * H1n;                      // N*8
  float* h2    = ad1 + (size_t)Nn * H1n;                      // N*16
  float* as2   = h2 + (size_t)Nn * OUT_CH;                    // N
  float* ad2   = as2 + Nn;                                    // N
  int* csr  = (int*)(ad2 + Nn);                               // E+N
  int* cnt  = csr + EPn;                                      // N  (cnt|cur adjacent)
  int* cur  = cnt + Nn;                                       // N
  int* rowp = cur + Nn;                                       // N+1

  hipMemsetAsync(cnt, 0, 2 * Nn * sizeof(int), stream);

  cvtwh_kernel<<<(NW8 + NW28 + NH4 + 255) / 256, 256, 0, stream>>>(
      W1, w_b, W2, w2b, ei, cnt);

  gemm1_mfma<<<640, 256, 0, stream>>>(x, w_b, asv1, adv1, h1b, as1, ad1);

  scan_kernel<<<1, 1024, 1000 * 21 * sizeof(int), stream>>>(cnt, rowp);
  scatter_kernel<<<(EPn / 4 + 255) / 256, 256, 0, stream>>>(ei, rowp, cur, csr);
  agg1_kernel<<<Nn / 2, 256, 0, stream>>>(rowp, csr, h1b, as1, ad1, b1,
                                          w2b, asv2, adv2, h2, as2, ad2);
  agg2_kernel<<<Nn / 4, 256, 0, stream>>>(rowp, csr, h2, as2, ad2, b2, out);
}